// Round 8
// baseline (94.595 us; speedup 1.0000x reference)
//
#include <hip/hip_runtime.h>
#include <hip/hip_bf16.h>

#define N_PIX 8192
#define C_DIM 128
#define HW 4096
// exp(dot/0.1) = exp2(dot * 14.42695...); fold sqrt of that into each vector.
#define PRESCALE 3.7982825f  // sqrt(log2(e)/0.1)
#define NUM_CLASSES 4
#define NSLOT 65  // 33 row-side slots (d=1..32 -> 0..31, diag -> 32) + 32 col-side (33..64)

typedef __attribute__((ext_vector_type(8))) short short8;   // 8 x bf16 (4 VGPRs)
typedef __attribute__((ext_vector_type(4))) float float4v;  // 4 x f32 acc

// Fragment-linear layout (R7 win): ebfT[((T*4 + s)*64 + lane)*8 + j] = e[T*16 + lq][s*32 + quad*8 + j],
// lane = quad*16 + lq. Fragment load = base + lane*16B: one coalesced 1KB dwordx4.

// ---------------- Kernel 1: L2-normalize + prescale + bf16 cast into ebfT; zero class accums ----------------
__global__ __launch_bounds__(256) void normscale_kernel(const float* __restrict__ emb,
                                                        unsigned short* __restrict__ ebfT,
                                                        unsigned* __restrict__ czero) {
    const int tid = threadIdx.x;
    const int p16 = tid & 15;   // pixel within tile (lq)
    const int g = tid >> 4;     // channel group 0..15 (8 channels each)
    const int n = blockIdx.x * 16 + p16;
    const int b = n >> 12;
    const int hw = n & (HW - 1);
    const float* base = emb + b * (C_DIM * HW) + hw;

    float v[8];
    float ss = 0.f;
#pragma unroll
    for (int i = 0; i < 8; ++i) {
        v[i] = base[(g * 8 + i) * HW];
        ss += v[i] * v[i];
    }
    ss += __shfl_xor(ss, 16, 64);
    ss += __shfl_xor(ss, 32, 64);
    __shared__ float red[4][16];
    const int wv = tid >> 6;
    if ((tid & 63) < 16) red[wv][p16] = ss;
    __syncthreads();
    float tot = red[0][p16] + red[1][p16] + red[2][p16] + red[3][p16];
    float inv = PRESCALE / fmaxf(sqrtf(tot), 1e-12f);

    unsigned short us[8];
#pragma unroll
    for (int i = 0; i < 8; ++i) {
        __hip_bfloat16 h = __float2bfloat16(v[i] * inv);
        us[i] = *reinterpret_cast<unsigned short*>(&h);
    }
    const int s = g >> 2, quad = g & 3;
    unsigned short* dst = ebfT + (((blockIdx.x * 4 + s) * 64 + quad * 16 + p16) << 3);
    *reinterpret_cast<short8*>(dst) = *reinterpret_cast<short8*>(us);

    // zero csum[4], ccnt[4], cnt (9 words) — the ONLY state needing init now
    if (blockIdx.x == 0 && tid < 9) czero[tid] = 0u;
}

// ---------------- Kernel 2: symmetric fused S = e e^T, exp2, row+col partial sums ----------------
// Grid (64, 33): bi = I-panel (128 rows).
//   d = blockIdx.y+1 in 1..32: off-diag pair blocks, jp=(bi+d)%64 (d=32 double-covers ->
//   bi>=32 culled). d == 33: dedicated diagonal blocks (R20).
// R21 (this round): ATOMIC-FREE TAIL. Previously ~666K device-scope lane-atomics hit 512
//   cachelines at the coherence point; equal-duration blocks made them a synchronized
//   end-of-kernel burst (suspected ~10+us of machine-idle serialization; R14's 4x atomic
//   cut = our biggest win supports the mechanism). Now every block writes its reduced
//   partials to a UNIQUE slot of part[NSLOT][8192] with plain fire-and-forget stores:
//     row-side -> slot d-1 (diag d=33 -> slot 32), col-side -> slot 32+d.
//   No pos/tot arrays, no zeroing (all valid slots written unconditionally; the two
//   cull-shadow regions are excluded block-uniformly in the reducer):
//     slot 31 (d=32 row): only rows < 4096 valid. slot 64 (d=32 col): only rows >= 4096.
// R14: col-side partials -> LDS per tile, reduced once per block after ONE __syncthreads.
// R15 FAILED (144us): __threadfence = L2 writeback+INVALIDATE poisoned ebfT reuse. NO
//   threadfence ever; cross-kernel visibility via kernel-boundary release/acquire only.
// R16 NEUTRAL: manual B-pipeline (latency already hidden). R20 NEUTRAL: diag straggler split.
// R17/R18 FAILED: __launch_bounds__ min-waves > 4 ALWAYS spills this kernel. (256,4) final.
// HARD-WON toolchain rules:
//   *** NEVER fully `#pragma unroll` the MFMA tile loop *** (hoists all B loads -> spill).
//   `#pragma unroll 2` is the sweet spot. R5: no global_load_lds here. R6: no lambdas;
//   reg arrays statically indexed only.
__global__ __launch_bounds__(256, 4) void pairwise_kernel(const unsigned short* __restrict__ ebfT,
                                                          const int* __restrict__ lab,
                                                          float* __restrict__ tpart,
                                                          float* __restrict__ ppart) {
    const int bi = blockIdx.x;
    const int d = blockIdx.y + 1;          // 1..33
    if (d == 32 && bi >= 32) return;       // wrap double-cover cull (block-uniform)
    const bool diag = (d == 33);           // dedicated diagonal blocks (block-uniform)
    const int jp = diag ? bi : ((bi + d) & 63);
    const int Ipanel = bi << 7;
    const int Jpanel = jp << 7;

    const int wave = threadIdx.x >> 6;
    const int lane = threadIdx.x & 63;
    const int quad = lane >> 4;
    const int lq = lane & 15;

    const int I0 = Ipanel + wave * 32;

    // [wave][tile][lane] col-side partials (x=tot, y=pos). 16 KiB.
    __shared__ float2 cpart[4][8][64];

    // A fragments: tiles (I0>>4), (I0>>4)+1 — coalesced lane*16B loads.
    short8 afrag[2][4];
#pragma unroll
    for (int a = 0; a < 2; ++a) {
        const unsigned short* ab = ebfT + ((((I0 >> 4) + a) * 4) * 64 + lane) * 8;
#pragma unroll
        for (int s = 0; s < 4; ++s)
            afrag[a][s] = *reinterpret_cast<const short8*>(ab + s * 512);
    }
    int lab_row[2][4];
#pragma unroll
    for (int a = 0; a < 2; ++a)
#pragma unroll
        for (int r = 0; r < 4; ++r) lab_row[a][r] = lab[I0 + a * 16 + quad * 4 + r];

    float tacc[2][4] = {};
    float pacc[2][4] = {};

    if (!diag) {
        // ---- Off-diagonal panel pair (no masking, row + col side) ----
        const unsigned short* bbase = ebfT + ((Jpanel >> 4) * 4 * 64 + lane) * 8;
#pragma unroll 2
        for (int t = 0; t < 8; ++t) {
            const int lab_col = lab[Jpanel + t * 16 + lq];
            const unsigned short* bt = bbase + t * 2048;
            short8 bfrag[4];
#pragma unroll
            for (int s = 0; s < 4; ++s)
                bfrag[s] = *reinterpret_cast<const short8*>(bt + s * 512);

            float4v acc0 = {0.f, 0.f, 0.f, 0.f};
            float4v acc1 = {0.f, 0.f, 0.f, 0.f};
#pragma unroll
            for (int s = 0; s < 4; ++s) {
                acc0 = __builtin_amdgcn_mfma_f32_16x16x32_bf16(afrag[0][s], bfrag[s], acc0, 0, 0, 0);
                acc1 = __builtin_amdgcn_mfma_f32_16x16x32_bf16(afrag[1][s], bfrag[s], acc1, 0, 0, 0);
            }

            float colTs = 0.f, colPs = 0.f;
#pragma unroll
            for (int r = 0; r < 4; ++r) {
                float ex = __builtin_amdgcn_exp2f(acc0[r]);
                tacc[0][r] += ex;
                float pxe = (lab_row[0][r] == lab_col) ? ex : 0.f;
                pacc[0][r] += pxe;
                colTs += ex;
                colPs += pxe;
            }
#pragma unroll
            for (int r = 0; r < 4; ++r) {
                float ex = __builtin_amdgcn_exp2f(acc1[r]);
                tacc[1][r] += ex;
                float pxe = (lab_row[1][r] == lab_col) ? ex : 0.f;
                pacc[1][r] += pxe;
                colTs += ex;
                colPs += pxe;
            }
            // fire-and-forget ds_write_b64; reduction deferred to post-barrier gather.
            cpart[wave][t][lane] = make_float2(colTs, colPs);
        }
    } else {
        // ---- Diagonal panel (self-masked, row-side only; col sums == row sums by symmetry) ----
#define EPILOGUE(A, ACC, MASKED)                                            \
    {                                                                       \
        _Pragma("unroll") for (int r = 0; r < 4; ++r) {                     \
            float ex = __builtin_amdgcn_exp2f(ACC[r]);                      \
            if (MASKED) ex = (lq == quad * 4 + r) ? 0.f : ex;               \
            tacc[A][r] += ex;                                               \
            pacc[A][r] += (lab_row[A][r] == lab_col) ? ex : 0.f;            \
        }                                                                   \
    }
        const unsigned short* bbase = ebfT + ((Ipanel >> 4) * 4 * 64 + lane) * 8;
#pragma unroll 2
        for (int t = 0; t < 8; ++t) {
            const int J = Ipanel + t * 16;
            const int lab_col = lab[J + lq];
            const unsigned short* bt = bbase + t * 2048;
            short8 bfrag[4];
#pragma unroll
            for (int s = 0; s < 4; ++s)
                bfrag[s] = *reinterpret_cast<const short8*>(bt + s * 512);

            float4v acc0 = {0.f, 0.f, 0.f, 0.f};
            float4v acc1 = {0.f, 0.f, 0.f, 0.f};
#pragma unroll
            for (int s = 0; s < 4; ++s) {
                acc0 = __builtin_amdgcn_mfma_f32_16x16x32_bf16(afrag[0][s], bfrag[s], acc0, 0, 0, 0);
                acc1 = __builtin_amdgcn_mfma_f32_16x16x32_bf16(afrag[1][s], bfrag[s], acc1, 0, 0, 0);
            }
            if (J == I0) EPILOGUE(0, acc0, true) else EPILOGUE(0, acc0, false);
            if (J == I0 + 16) EPILOGUE(1, acc1, true) else EPILOGUE(1, acc1, false);
        }
#undef EPILOGUE
    }

    // ---- Row-side flush: plain stores to this block's unique slot (d-1; diag -> 32) ----
    {
        float* trow = tpart + (d - 1) * N_PIX;
        float* prow = ppart + (d - 1) * N_PIX;
#pragma unroll
        for (int a = 0; a < 2; ++a) {
#pragma unroll
            for (int r = 0; r < 4; ++r) {
                float t = tacc[a][r], p = pacc[a][r];
#pragma unroll
                for (int off = 1; off < 16; off <<= 1) {
                    t += __shfl_xor(t, off, 64);
                    p += __shfl_xor(p, off, 64);
                }
                if (lq == 0) {
                    const int row = I0 + a * 16 + quad * 4 + r;
                    trow[row] = t;
                    prow[row] = p;
                }
            }
        }
    }

    // ---- Col-side gather (off-diag only): plain coalesced stores to slot 32+d ----
    if (!diag) {
        __syncthreads();
        if (threadIdx.x < 128) {
            const int j = threadIdx.x;          // column within J panel
            const int tt = j >> 4, jl = j & 15; // tile, lane-within-tile
            float st = 0.f, sp = 0.f;
#pragma unroll
            for (int w = 0; w < 4; ++w)
#pragma unroll
                for (int q = 0; q < 4; ++q) {
                    float2 v = cpart[w][tt][q * 16 + jl];
                    st += v.x;
                    sp += v.y;
                }
            tpart[(32 + d) * N_PIX + Jpanel + j] = st;
            ppart[(32 + d) * N_PIX + Jpanel + j] = sp;
        }
    }
}

// ---------------- Kernel 3: slot reduce + row losses + per-class mean (last-block final) ----------------
// 64 blocks x 128 threads; thread = one row. Coalesced 512B reads per slot. Each row sums
// exactly 64 valid slots: slots {0..30, 32..63} always; slot 31 iff row<4096 (d=32 row-side
// was written only by bi<32), else slot 64 (d=32 col-side covers jp>=32). Block-uniform.
// Completion via acq_rel atomic counter — NOT __threadfence (R15 rule): release = waitcnt,
// no cache invalidate; csum/ccnt live at the coherence point (atomics), read back with
// agent-scope atomic loads.
__global__ __launch_bounds__(128) void reduce_kernel(const float* __restrict__ tpart,
                                                     const float* __restrict__ ppart,
                                                     const int* __restrict__ lab,
                                                     float* __restrict__ csum,
                                                     float* __restrict__ ccnt,
                                                     unsigned* __restrict__ cnt,
                                                     float* __restrict__ out) {
    const int bi = blockIdx.x;                 // 0..63
    const int tid = threadIdx.x;               // 0..127
    const int row = bi * 128 + tid;
    const bool lowhalf = (bi < 32);

    float ts = 0.f, ps = 0.f;
#pragma unroll 8
    for (int s = 0; s < 64; ++s) {
        const int slot = (s == 31) ? (lowhalf ? 31 : 64) : s;
        ts += tpart[slot * N_PIX + row];
        ps += ppart[slot * N_PIX + row];
    }
    const float rl = logf(ts + 1e-6f) - logf(ps);
    const int c = lab[row];

    float ls[NUM_CLASSES], lc[NUM_CLASSES];
#pragma unroll
    for (int k = 0; k < NUM_CLASSES; ++k) {
        ls[k] = (c == k) ? rl : 0.f;
        lc[k] = (c == k) ? 1.f : 0.f;
    }
#pragma unroll
    for (int off = 1; off < 64; off <<= 1) {
#pragma unroll
        for (int k = 0; k < NUM_CLASSES; ++k) {
            ls[k] += __shfl_xor(ls[k], off, 64);
            lc[k] += __shfl_xor(lc[k], off, 64);
        }
    }
    __shared__ float ssum[2][NUM_CLASSES];
    __shared__ float scnt[2][NUM_CLASSES];
    const int wid = tid >> 6;
    if ((tid & 63) == 0) {
#pragma unroll
        for (int k = 0; k < NUM_CLASSES; ++k) {
            ssum[wid][k] = ls[k];
            scnt[wid][k] = lc[k];
        }
    }
    __syncthreads();
    if (tid == 0) {
#pragma unroll
        for (int k = 0; k < NUM_CLASSES; ++k) {
            atomicAdd(&csum[k], ssum[0][k] + ssum[1][k]);
            atomicAdd(&ccnt[k], scnt[0][k] + scnt[1][k]);
        }
    }

    __shared__ unsigned slast;
    if (tid == 0)
        slast = (__hip_atomic_fetch_add(cnt, 1u, __ATOMIC_ACQ_REL, __HIP_MEMORY_SCOPE_AGENT) == 63u)
                    ? 1u : 0u;
    __syncthreads();
    if (slast == 0u) return;

    if (tid == 0) {
        float acc = 0.f;
        int present = 0;
        for (int k = 0; k < NUM_CLASSES; ++k) {
            float s = __hip_atomic_load(&csum[k], __ATOMIC_RELAXED, __HIP_MEMORY_SCOPE_AGENT);
            float c2 = __hip_atomic_load(&ccnt[k], __ATOMIC_RELAXED, __HIP_MEMORY_SCOPE_AGENT);
            if (c2 > 0.f) {
                acc += s / c2;
                present++;
            }
        }
        out[0] = acc / (float)(present > 0 ? present : 1);
    }
}

extern "C" void kernel_launch(void* const* d_in, const int* in_sizes, int n_in,
                              void* d_out, int out_size, void* d_ws, size_t ws_size,
                              hipStream_t stream) {
    const float* emb = (const float*)d_in[0];  // [2,128,64,64] fp32
    const int* lab = (const int*)d_in[1];      // [2,64,64] int32
    float* out = (float*)d_out;

    unsigned short* ebfT = (unsigned short*)d_ws;              // 2 MiB
    float* tpart = (float*)((char*)d_ws + N_PIX * C_DIM * 2);  // [65][8192] f32
    float* ppart = tpart + NSLOT * N_PIX;                      // [65][8192] f32
    float* csum = ppart + NSLOT * N_PIX;                       // [4]
    float* ccnt = csum + NUM_CLASSES;                          // [4]
    unsigned* cnt = (unsigned*)(ccnt + NUM_CLASSES);           // completion counter

    normscale_kernel<<<N_PIX / 16, 256, 0, stream>>>(emb, ebfT, (unsigned*)csum);

    dim3 grid(64, 33);  // 1..32 off-diag pair cover + 33rd row = diagonal-only blocks
    pairwise_kernel<<<grid, 256, 0, stream>>>(ebfT, lab, tpart, ppart);

    reduce_kernel<<<64, 128, 0, stream>>>(tpart, ppart, lab, csum, ccnt, cnt, out);
}